// Round 5
// baseline (137.475 us; speedup 1.0000x reference)
//
#include <hip/hip_runtime.h>
#include <math.h>

// Problem constants (B, NP, NQ, D) = (4, 256, 256, 512)
#define BB   4
#define NP   256
#define NQ   256
#define DD   512
#define DD4  (DD / 4)

typedef float f32x4 __attribute__((ext_vector_type(4)));

static constexpr float kScale = 1.0f / 22.627417f;  // 1/sqrt(512)

// ---------------------------------------------------------------------------
// Fused kernel, grid.x = 768:
//  blocks [0, 512):   two (b,n) pairs each (n0 = even n). Compute both
//                     query_attn rows in-block (qk row loaded once per thread,
//                     dotted vs both qq rows), block softmax -> transposed
//                     gate float2 in LDS, then the gated-combine streaming
//                     write of out[b,n0,:,:] and out[b,n0+1,:,:] — each v
//                     load feeds two nontemporal stores.
//  blocks [512, 768): 4 p-rows each of attn/log_attn = softmax(q.k^T/T).
// ---------------------------------------------------------------------------
__global__ __launch_bounds__(256) void fused_qgsa2_kernel(
    const float* __restrict__ q,     // [B, NP, D]
    const float* __restrict__ k,     // [B, NP, D]
    const f32x4* __restrict__ v4,    // [B, NP, DD4]
    const float* __restrict__ qq,    // [B, NQ, D]
    const float* __restrict__ qk,    // [B, NP, D]
    const f32x4* __restrict__ qv4,   // [B, NQ, DD4]
    f32x4* __restrict__ out4,        // [B, NQ, NP, DD4]
    float* __restrict__ attn_out,    // [B, NP, NP]
    float* __restrict__ logattn_out) // [B, NP, NP]
{
    __shared__ __align__(16) float smem[4 * 256];   // A: ss[2][256] + gt[256][2]
    const int t = threadIdx.x;

    if (blockIdx.x < 512u) {
        // ---------------- type A: 2 gates + streaming write ----------------
        const int b  = blockIdx.x >> 7;
        const int n0 = (blockIdx.x & 127) * 2;

        // q_scores[b,n0+r,t] = dot(qq[b,n0+r,:], qk[b,t,:]) * kScale
        {
            const f32x4* krow = (const f32x4*)(qk + ((size_t)b * NP + t) * DD);
            const float* qb   = qq + ((size_t)b * NQ + n0) * DD;  // wave-uniform
            float acc0 = 0.f, acc1 = 0.f;
            #pragma unroll 8
            for (int d4 = 0; d4 < DD4; ++d4) {
                const f32x4 kv = krow[d4];
                const float* q0 = qb + d4 * 4;
                const float* q1 = qb + DD + d4 * 4;
                acc0 += q0[0] * kv.x + q0[1] * kv.y + q0[2] * kv.z + q0[3] * kv.w;
                acc1 += q1[0] * kv.x + q1[1] * kv.y + q1[2] * kv.z + q1[3] * kv.w;
            }
            smem[t]       = acc0 * kScale;
            smem[256 + t] = acc1 * kScale;
        }
        __syncthreads();

        // Row softmax: waves 0,2 -> row 0; waves 1,3 -> row 1 (duplicate ok).
        {
            const int r = (t >> 6) & 1;
            const int g = t & 63;
            const f32x4 sv = ((const f32x4*)(smem + r * 256))[g];

            float m = fmaxf(fmaxf(sv.x, sv.y), fmaxf(sv.z, sv.w));
            #pragma unroll
            for (int off = 32; off >= 1; off >>= 1)
                m = fmaxf(m, __shfl_xor(m, off, 64));

            f32x4 ev;
            ev.x = expf(sv.x - m); ev.y = expf(sv.y - m);
            ev.z = expf(sv.z - m); ev.w = expf(sv.w - m);
            float s = (ev.x + ev.y) + (ev.z + ev.w);
            #pragma unroll
            for (int off = 32; off >= 1; off >>= 1) s += __shfl_xor(s, off, 64);

            const float inv = 1.0f / s;
            float* gtf = smem + 512;            // [256][2] transposed gates
            gtf[(4 * g + 0) * 2 + r] = ev.x * inv;
            gtf[(4 * g + 1) * 2 + r] = ev.y * inv;
            gtf[(4 * g + 2) * 2 + r] = ev.z * inv;
            gtf[(4 * g + 3) * 2 + r] = ev.w * inv;
        }
        __syncthreads();

        // out[b,n0+r,p,:] = gate[r][p] * (v[b,p,:] + qv[b,n0+r,:])
        const int d4 = t & (DD4 - 1);
        const int po = t >> 7;                  // 0 or 1
        const f32x4 qvr0 = qv4[((size_t)b * NQ + n0) * DD4 + d4];
        const f32x4 qvr1 = qv4[((size_t)b * NQ + n0 + 1) * DD4 + d4];
        const f32x4* vcol = v4 + (size_t)b * NP * DD4 + d4;
        f32x4* ocol = out4 + ((size_t)b * NQ + n0) * ((size_t)NP * DD4) + d4;
        const float2* gt2 = (const float2*)(smem + 512);

        #pragma unroll 4
        for (int p = po; p < NP; p += 2) {
            const f32x4 vv = vcol[(size_t)p * DD4];
            const float2 g2 = gt2[p];           // broadcast (uniform address)
            __builtin_nontemporal_store((vv + qvr0) * g2.x,
                                        ocol + (size_t)p * DD4);
            __builtin_nontemporal_store((vv + qvr1) * g2.y,
                                        ocol + (size_t)(NP * DD4) + (size_t)p * DD4);
        }
    } else {
        // ---------------- type B: attn / log_attn softmax ----------------
        const int idx = blockIdx.x - 512;       // 0..255
        const int b   = idx >> 6;
        const int p0  = (idx & 63) * 4;

        const f32x4* krow = (const f32x4*)(k + ((size_t)b * NP + t) * DD);
        const float* qb   = q + ((size_t)b * NP + p0) * DD;   // wave-uniform

        float acc[4] = {0.f, 0.f, 0.f, 0.f};
        #pragma unroll 8
        for (int d4 = 0; d4 < DD4; ++d4) {
            const f32x4 kv = krow[d4];
            #pragma unroll
            for (int r = 0; r < 4; ++r) {
                const float* qr = qb + r * DD + d4 * 4;
                acc[r] += qr[0] * kv.x + qr[1] * kv.y + qr[2] * kv.z + qr[3] * kv.w;
            }
        }

        float (*ss)[256] = (float (*)[256])smem;
        #pragma unroll
        for (int r = 0; r < 4; ++r) ss[r][t] = acc[r] * kScale;
        __syncthreads();

        const int r = t >> 6;
        const int g = t & 63;
        const f32x4 sv = ((const f32x4*)ss[r])[g];

        float m = fmaxf(fmaxf(sv.x, sv.y), fmaxf(sv.z, sv.w));
        #pragma unroll
        for (int off = 32; off >= 1; off >>= 1)
            m = fmaxf(m, __shfl_xor(m, off, 64));

        f32x4 ev;
        ev.x = expf(sv.x - m); ev.y = expf(sv.y - m);
        ev.z = expf(sv.z - m); ev.w = expf(sv.w - m);
        float s = (ev.x + ev.y) + (ev.z + ev.w);
        #pragma unroll
        for (int off = 32; off >= 1; off >>= 1) s += __shfl_xor(s, off, 64);

        const float inv = 1.0f / s;
        const float lse = logf(s);

        const size_t base = ((size_t)b * NP + (p0 + r)) * 256;
        ((f32x4*)(attn_out + base))[g] = ev * inv;
        f32x4 lg;
        lg.x = (sv.x - m) - lse; lg.y = (sv.y - m) - lse;
        lg.z = (sv.z - m) - lse; lg.w = (sv.w - m) - lse;
        ((f32x4*)(logattn_out + base))[g] = lg;
    }
}

extern "C" void kernel_launch(void* const* d_in, const int* in_sizes, int n_in,
                              void* d_out, int out_size, void* d_ws, size_t ws_size,
                              hipStream_t stream) {
    // setup_inputs order: q, k, v, query(unused), query_q, query_k, query_v
    const float* q  = (const float*)d_in[0];
    const float* k  = (const float*)d_in[1];
    const float* v  = (const float*)d_in[2];
    const float* qq = (const float*)d_in[4];
    const float* qk = (const float*)d_in[5];
    const float* qv = (const float*)d_in[6];

    float* out = (float*)d_out;
    const size_t out_elems = (size_t)BB * NQ * NP * DD;          // 134,217,728
    float* attn_out    = out + out_elems;                         // [B,NP,256]
    float* logattn_out = attn_out + (size_t)BB * NP * 256;        // [B,NP,256]

    fused_qgsa2_kernel<<<768, 256, 0, stream>>>(
        q, k, (const f32x4*)v, qq, qk, (const f32x4*)qv,
        (f32x4*)out, attn_out, logattn_out);
}